// Round 8
// baseline (558.747 us; speedup 1.0000x reference)
//
#include <hip/hip_runtime.h>
#include <hip/hip_bf16.h>
#include <math.h>

#define NN 50000
#define EE 800000
// NF=128, EF=64, S=128; NN/16 = 3125 row-tiles exactly; EE/256 = 3125

typedef __bf16 bf16x8 __attribute__((ext_vector_type(8)));
typedef float f32x4 __attribute__((ext_vector_type(4)));
typedef unsigned int u32x4 __attribute__((ext_vector_type(4)));

// ---------------- fused: deg histogram (blocks >=128) + weight prep (blocks 0..127) ----------------
__global__ void k_deg_wprep(const int* __restrict__ ei, int* __restrict__ deg,
                            const float* __restrict__ Wzc, const float* __restrict__ bzc,
                            const float* __restrict__ Wzl, const float* __restrict__ bzl,
                            const float* __restrict__ Whc, const float* __restrict__ bhc,
                            const float* __restrict__ Whl, const float* __restrict__ bhl,
                            float* __restrict__ Wcat, float* __restrict__ cb) {
    if (blockIdx.x < 128) {
        int i = blockIdx.x;      // fan-in row (uniform -> scalar loads of Wzc/Whc)
        int k = threadIdx.x;     // out col (coalesced over Wzl/Whl)
        if (k < 128) {
            float sz = 0.f, sh = 0.f;
            for (int j = 0; j < 128; j++) {
                sz += Wzc[i * 128 + j] * Wzl[j * 128 + k];
                sh += Whc[i * 128 + j] * Whl[j * 128 + k];
            }
            Wcat[i * 256 + 2 * k]     = sz;
            Wcat[i * 256 + 2 * k + 1] = sh;
            if (i == 0) {
                float bz = bzl[k], bh = bhl[k];
                for (int j = 0; j < 128; j++) {
                    bz += bzc[j] * Wzl[j * 128 + k];
                    bh += bhc[j] * Whl[j * 128 + k];
                }
                cb[2 * k]     = bz;
                cb[2 * k + 1] = bh;
            }
        }
    } else {
        int e = (blockIdx.x - 128) * 256 + threadIdx.x;
        if (e < EE) atomicAdd(&deg[ei[EE + e]], 1);
    }
}

// ---------------- GEMM1 via MFMA: xs[N,128] = bf16( relu(x @ Wn + bn) * dinv ) ----------------
__global__ __launch_bounds__(256) void k_g1_mfma(const float* __restrict__ x,
                                                 const float* __restrict__ Wn,
                                                 const float* __restrict__ bn,
                                                 const int* __restrict__ deg,
                                                 __hip_bfloat16* __restrict__ xs) {
    const int lane = threadIdx.x & 63;
    const int ln = lane & 15;
    const int q  = lane >> 4;
    const int wid = (blockIdx.x * 256 + threadIdx.x) >> 6;
    const int nw  = gridDim.x * 4;
    const int ch  = wid & 1;          // column half
    const int step = nw >> 1;

    bf16x8 bfrag[4][4];               // [t][kc]: B[k=kc*32+q*8+j][col=ch*64+t*16+ln]
#pragma unroll
    for (int t = 0; t < 4; t++)
#pragma unroll
        for (int kc = 0; kc < 4; kc++)
#pragma unroll
            for (int j = 0; j < 8; j++)
                bfrag[t][kc][j] = (__bf16)Wn[(kc * 32 + q * 8 + j) * 128 + ch * 64 + t * 16 + ln];
    float biasR[4];
#pragma unroll
    for (int t = 0; t < 4; t++) biasR[t] = bn[ch * 64 + t * 16 + ln];

    for (int rt = wid >> 1; rt < 3125; rt += step) {
        const int e0 = rt * 16;
        const float* arow = x + (size_t)(e0 + ln) * 128;
        bf16x8 af[4];
#pragma unroll
        for (int kc = 0; kc < 4; kc++) {
            float4 v0 = *(const float4*)(arow + kc * 32 + q * 8);
            float4 v1 = *(const float4*)(arow + kc * 32 + q * 8 + 4);
            af[kc][0] = (__bf16)v0.x; af[kc][1] = (__bf16)v0.y;
            af[kc][2] = (__bf16)v0.z; af[kc][3] = (__bf16)v0.w;
            af[kc][4] = (__bf16)v1.x; af[kc][5] = (__bf16)v1.y;
            af[kc][6] = (__bf16)v1.z; af[kc][7] = (__bf16)v1.w;
        }
        f32x4 acc[4];
#pragma unroll
        for (int t = 0; t < 4; t++) acc[t] = (f32x4){0.f, 0.f, 0.f, 0.f};
#pragma unroll
        for (int t = 0; t < 4; t++)
#pragma unroll
            for (int kc = 0; kc < 4; kc++)
                acc[t] = __builtin_amdgcn_mfma_f32_16x16x32_bf16(af[kc], bfrag[t][kc], acc[t], 0, 0, 0);

        float diR[4];
#pragma unroll
        for (int r = 0; r < 4; r++) diR[r] = rsqrtf((float)(deg[e0 + q * 4 + r] + 1));
#pragma unroll
        for (int t = 0; t < 4; t++)
#pragma unroll
            for (int r = 0; r < 4; r++) {
                float v = fmaxf(acc[t][r] + biasR[t], 0.f) * diR[r];
                xs[(size_t)(e0 + q * 4 + r) * 128 + ch * 64 + t * 16 + ln] = __float2bfloat16(v);
            }
    }
}

// ---------------- gate GEMM via MFMA + gates + projection (block-cooperative, no atomics) ----------------
// Block = 4 waves; wave w handles column-quarter w of the SAME 16-row tile.
// Partial (a,b) reduced via LDS; plain stores (every node written exactly once).
__global__ __launch_bounds__(256) void k_gate_mfma(const unsigned int* __restrict__ aggu,
                                                   const float* __restrict__ Wcat,
                                                   const float* __restrict__ cb,
                                                   const float* __restrict__ Wout,
                                                   float* __restrict__ aArr,
                                                   float* __restrict__ bArr) {
    __shared__ float red[4][32];
    const int tid = threadIdx.x;
    const int lane = tid & 63;
    const int ln = lane & 15;
    const int q  = lane >> 4;
    const int w  = tid >> 6;          // wave index == column quarter

    bf16x8 bfrag[4][4];               // [t][kc]: Wcat[k=kc*32+q*8+j][col=w*64+t*16+ln]
#pragma unroll
    for (int t = 0; t < 4; t++)
#pragma unroll
        for (int kc = 0; kc < 4; kc++)
#pragma unroll
            for (int j = 0; j < 8; j++)
                bfrag[t][kc][j] = (__bf16)Wcat[(kc * 32 + q * 8 + j) * 256 + w * 64 + t * 16 + ln];

    float cbR[4], wAR[4], wBR[4];
#pragma unroll
    for (int t = 0; t < 4; t++) {
        int col = w * 64 + t * 16 + ln;
        cbR[t] = cb[col];
        int k = col >> 1;             // meaningful on even lanes only
        wAR[t] = Wout[k];
        wBR[t] = Wout[128 + k];
    }
    const bool odd = (ln & 1);

    for (int rt = blockIdx.x; rt < 3125; rt += gridDim.x) {
        const int e0 = rt * 16;
        const u32x4* arow = (const u32x4*)aggu + (size_t)(e0 + ln) * 16;
        bf16x8 af[4];
#pragma unroll
        for (int kc = 0; kc < 4; kc++) {
            u32x4 uv = arow[kc * 4 + q];
            af[kc] = __builtin_bit_cast(bf16x8, uv);
        }
        f32x4 acc[4];
#pragma unroll
        for (int t = 0; t < 4; t++) acc[t] = (f32x4){0.f, 0.f, 0.f, 0.f};
#pragma unroll
        for (int t = 0; t < 4; t++)
#pragma unroll
            for (int kc = 0; kc < 4; kc++)
                acc[t] = __builtin_amdgcn_mfma_f32_16x16x32_bf16(af[kc], bfrag[t][kc], acc[t], 0, 0, 0);

        float pa[4] = {0.f, 0.f, 0.f, 0.f};
        float pb[4] = {0.f, 0.f, 0.f, 0.f};
#pragma unroll
        for (int t = 0; t < 4; t++)
#pragma unroll
            for (int r = 0; r < 4; r++) {
                float val = acc[t][r] + cbR[t];
                float s = odd ? tanhf(val) : (1.f / (1.f + expf(-val)));
                float partner = __shfl_xor(s, 1);
                if (!odd) {
                    float h = (1.f - s) * partner;   // (1-z)*tanh(t)
                    pa[r] += h * wAR[t];
                    pb[r] += h * wBR[t];
                }
            }
        // butterfly within each 16-lane quad: all lanes end with quad totals
#pragma unroll
        for (int off = 1; off < 16; off <<= 1) {
#pragma unroll
            for (int r = 0; r < 4; r++) {
                pa[r] += __shfl_xor(pa[r], off);
                pb[r] += __shfl_xor(pb[r], off);
            }
        }
        __syncthreads();              // protect red[] reuse across iterations
        if (ln == 0) {
#pragma unroll
            for (int r = 0; r < 4; r++) {
                red[w][q * 4 + r]      = pa[r];
                red[w][16 + q * 4 + r] = pb[r];
            }
        }
        __syncthreads();
        if (tid < 32) {
            float sum = red[0][tid] + red[1][tid] + red[2][tid] + red[3][tid];
            if (tid < 16) aArr[e0 + tid] = sum;
            else          bArr[e0 + tid - 16] = sum;
        }
    }
}

// ---------------- single-dispatch scan: decoupled lookback (196 blocks, co-resident) ----------------
__global__ void k_scan(const int* __restrict__ deg, int* __restrict__ partial,
                       int* __restrict__ rowptr, int* __restrict__ cursor) {
    __shared__ int s[256];
    __shared__ int ps[256];
    const int b = blockIdx.x;
    const int i = b * 256 + threadIdx.x;
    int v = (i < NN) ? deg[i] : 0;
    s[threadIdx.x] = v;
    __syncthreads();
    // inclusive scan of s
    for (int off = 1; off < 256; off <<= 1) {
        int t = (threadIdx.x >= off) ? s[threadIdx.x - off] : 0;
        __syncthreads();
        s[threadIdx.x] += t;
        __syncthreads();
    }
    // publish block total (value+1; 0 = not ready; partial[] pre-zeroed)
    if (threadIdx.x == 255)
        __hip_atomic_store(&partial[b], s[255] + 1, __ATOMIC_RELEASE, __HIP_MEMORY_SCOPE_AGENT);
    // lookback: thread t < b spins on partial[t]
    int contrib = 0;
    if (threadIdx.x < b) {
        int pv;
        do {
            pv = __hip_atomic_load(&partial[threadIdx.x], __ATOMIC_ACQUIRE, __HIP_MEMORY_SCOPE_AGENT);
        } while (pv == 0);
        contrib = pv - 1;
    }
    ps[threadIdx.x] = contrib;
    __syncthreads();
    for (int off = 128; off > 0; off >>= 1) {
        if (threadIdx.x < off) ps[threadIdx.x] += ps[threadIdx.x + off];
        __syncthreads();
    }
    int excl = s[threadIdx.x] - v + ps[0];
    if (i < NN) { rowptr[i] = excl; cursor[i] = excl; }
    if (i == 0) rowptr[NN] = EE;
}

__global__ void k_fill(const int* __restrict__ ei, int* __restrict__ cursor,
                       int* __restrict__ col) {
    int e = blockIdx.x * 256 + threadIdx.x;
    if (e < EE) {
        int d = ei[EE + e];
        int p = atomicAdd(&cursor[d], 1);
        col[p] = ei[e];
    }
}

// ---------------- per-node gather on bf16 xs: one wave per node; masked 8-wide groups ----------------
__global__ __launch_bounds__(256) void k_gather(const unsigned int* __restrict__ xsu,
                                                const int* __restrict__ rowptr,
                                                const int* __restrict__ col,
                                                const int* __restrict__ deg,
                                                unsigned int* __restrict__ aggu) {
    int gt = blockIdx.x * 256 + threadIdx.x;
    int node = gt >> 6;
    int lane = threadIdx.x & 63;
    if (node >= NN) return;
    int beg = rowptr[node], end = rowptr[node + 1];
    unsigned int u = xsu[(size_t)node * 64 + lane];  // self loop
    float a0 = __uint_as_float(u << 16);
    float a1 = __uint_as_float(u & 0xFFFF0000u);
    for (int p = beg; p < end; p += 64) {
        int navail = end - p;                       // > 0
        int clamp = (lane < navail) ? lane : (navail - 1);
        int cv = col[p + clamp];
        int chunk = navail < 64 ? navail : 64;
        for (int j = 0; j < chunk; j += 8) {
#pragma unroll
            for (int jj = 0; jj < 8; jj++) {
                int s = __shfl(cv, j + jj);
                unsigned int uv = xsu[(size_t)s * 64 + lane];
                if (j + jj < chunk) {               // wave-uniform predicate
                    a0 += __uint_as_float(uv << 16);
                    a1 += __uint_as_float(uv & 0xFFFF0000u);
                }
            }
        }
    }
    float di = rsqrtf((float)(deg[node] + 1));
    __hip_bfloat16 b0 = __float2bfloat16(a0 * di);
    __hip_bfloat16 b1 = __float2bfloat16(a1 * di);
    unsigned int lo = *(unsigned short*)&b0;
    unsigned int hi = *(unsigned short*)&b1;
    aggu[(size_t)node * 64 + lane] = lo | (hi << 16);
}

// ---------------- per-edge fused GEMM via MFMA ----------------
__global__ __launch_bounds__(256) void k_edge_mfma(const float* __restrict__ EA,
                                                   const int* __restrict__ ei,
                                                   const float* __restrict__ We,
                                                   const float* __restrict__ be,
                                                   const float* __restrict__ Wout,
                                                   const float* __restrict__ boutp,
                                                   const float* __restrict__ aArr,
                                                   const float* __restrict__ bArr,
                                                   float* __restrict__ out) {
    const int lane = threadIdx.x & 63;
    const int ln = lane & 15;
    const int q  = lane >> 4;
    const int wid = (blockIdx.x * 256 + threadIdx.x) >> 6;
    const int nw  = gridDim.x * 4;

    bf16x8 bfrag[2][8];
#pragma unroll
    for (int h = 0; h < 2; h++)
#pragma unroll
        for (int t = 0; t < 8; t++)
#pragma unroll
            for (int j = 0; j < 8; j++)
                bfrag[h][t][j] = (__bf16)We[(h * 32 + q * 8 + j) * 128 + t * 16 + ln];

    float beR[8], w3R[8];
#pragma unroll
    for (int t = 0; t < 8; t++) {
        beR[t] = be[t * 16 + ln];
        w3R[t] = Wout[256 + t * 16 + ln];
    }
    const float b0 = boutp[0];

    for (int tile = wid; tile < EE / 16; tile += nw) {
        const int e0 = tile * 16;
        const float* arow = EA + (size_t)(e0 + ln) * 64;
        float4 v0 = *(const float4*)(arow + q * 8);
        float4 v1 = *(const float4*)(arow + q * 8 + 4);
        float4 v2 = *(const float4*)(arow + 32 + q * 8);
        float4 v3 = *(const float4*)(arow + 32 + q * 8 + 4);
        bf16x8 af0, af1;
        af0[0] = (__bf16)v0.x; af0[1] = (__bf16)v0.y; af0[2] = (__bf16)v0.z; af0[3] = (__bf16)v0.w;
        af0[4] = (__bf16)v1.x; af0[5] = (__bf16)v1.y; af0[6] = (__bf16)v1.z; af0[7] = (__bf16)v1.w;
        af1[0] = (__bf16)v2.x; af1[1] = (__bf16)v2.y; af1[2] = (__bf16)v2.z; af1[3] = (__bf16)v2.w;
        af1[4] = (__bf16)v3.x; af1[5] = (__bf16)v3.y; af1[6] = (__bf16)v3.z; af1[7] = (__bf16)v3.w;

        f32x4 acc[8];
#pragma unroll
        for (int t = 0; t < 8; t++) acc[t] = (f32x4){0.f, 0.f, 0.f, 0.f};
#pragma unroll
        for (int t = 0; t < 8; t++)
            acc[t] = __builtin_amdgcn_mfma_f32_16x16x32_bf16(af0, bfrag[0][t], acc[t], 0, 0, 0);
#pragma unroll
        for (int t = 0; t < 8; t++)
            acc[t] = __builtin_amdgcn_mfma_f32_16x16x32_bf16(af1, bfrag[1][t], acc[t], 0, 0, 0);

        float part[4] = {0.f, 0.f, 0.f, 0.f};
#pragma unroll
        for (int t = 0; t < 8; t++)
#pragma unroll
            for (int r = 0; r < 4; r++) {
                float y = acc[t][r] + beR[t];
                y = fmaxf(y, 0.f);
                part[r] += y * w3R[t];
            }
#pragma unroll
        for (int off = 1; off < 16; off <<= 1) {
#pragma unroll
            for (int r = 0; r < 4; r++) part[r] += __shfl_xor(part[r], off);
        }
        if (ln < 4) {
            float c = (ln == 0) ? part[0] : (ln == 1) ? part[1] : (ln == 2) ? part[2] : part[3];
            int e = e0 + q * 4 + ln;
            out[e] = c + aArr[ei[e]] + bArr[ei[EE + e]] + b0;
        }
    }
}

extern "C" void kernel_launch(void* const* d_in, const int* in_sizes, int n_in,
                              void* d_out, int out_size, void* d_ws, size_t ws_size,
                              hipStream_t stream) {
    const float* x    = (const float*)d_in[0];
    const int*   ei   = (const int*)d_in[1];
    const float* ea   = (const float*)d_in[2];
    const float* Wn   = (const float*)d_in[3];
    const float* bn   = (const float*)d_in[4];
    const float* We   = (const float*)d_in[5];
    const float* be   = (const float*)d_in[6];
    const float* Wzc  = (const float*)d_in[7];
    const float* bzc  = (const float*)d_in[8];
    const float* Wzl  = (const float*)d_in[9];
    const float* bzl  = (const float*)d_in[10];
    const float* Whc  = (const float*)d_in[15];
    const float* bhc  = (const float*)d_in[16];
    const float* Whl  = (const float*)d_in[17];
    const float* bhl  = (const float*)d_in[18];
    const float* Wout = (const float*)d_in[19];
    const float* bout = (const float*)d_in[20];
    float* out = (float*)d_out;

    char* w = (char*)d_ws;
    auto carve = [&](size_t bytes) {
        void* p = (void*)w;
        w += (bytes + 255) / 256 * 256;
        return p;
    };
    // zero-region: deg | partial contiguous (one memset covers both)
    int*   deg     = (int*)carve((size_t)NN * 4);
    int*   partial = (int*)carve(256 * 4);
    size_t zbytes  = (size_t)((char*)(partial + 256) - (char*)deg);
    float* aArr    = (float*)carve((size_t)NN * 4);
    float* bArr    = (float*)carve((size_t)NN * 4);
    __hip_bfloat16* xs = (__hip_bfloat16*)carve((size_t)NN * 128 * 2);
    unsigned int* aggu = (unsigned int*)carve((size_t)NN * 64 * 4);
    float* Wcat    = (float*)carve(128 * 256 * 4);
    float* cb      = (float*)carve(256 * 4);
    int*   rowptr  = (int*)carve((size_t)(NN + 1) * 4);
    int*   cursor  = (int*)carve((size_t)NN * 4);
    int*   col     = (int*)carve((size_t)EE * 4);

    hipMemsetAsync(deg, 0, zbytes, stream);

    // deg histogram + fused-weight prep in one dispatch
    k_deg_wprep<<<128 + 3125, 256, 0, stream>>>(ei, deg, Wzc, bzc, Wzl, bzl,
                                                Whc, bhc, Whl, bhl, Wcat, cb);

    // xs = bf16( relu(x @ Wn + bn) * dinv[row] )   [MFMA]
    k_g1_mfma<<<384, 256, 0, stream>>>(x, Wn, bn, deg, xs);

    // CSR build: single-dispatch decoupled-lookback scan + fill
    const int NB = (NN + 255) / 256;  // 196 blocks (co-resident on 256 CUs)
    k_scan<<<NB, 256, 0, stream>>>(deg, partial, rowptr, cursor);
    k_fill<<<3125, 256, 0, stream>>>(ei, cursor, col);

    // agg (packed bf16) = dinv[row] * (sum_in xs[src] + xs[row])
    k_gather<<<(NN * 64 + 255) / 256, 256, 0, stream>>>((const unsigned int*)xs, rowptr, col, deg, aggu);

    // gates + projection, block-cooperative MFMA (no atomics) -> aArr, bArr
    k_gate_mfma<<<512, 256, 0, stream>>>(aggu, Wcat, cb, Wout, aArr, bArr);

    // per-edge fused output
    k_edge_mfma<<<2048, 256, 0, stream>>>(ea, ei, We, be, Wout, bout, aArr, bArr, out);
}